// Round 3
// baseline (27570.004 us; speedup 1.0000x reference)
//
#include <hip/hip_runtime.h>
#include <stdint.h>

#define B_  16
#define T_  1024
#define H_  1024
#define E_  512
#define V_  256
#define C_  256

typedef __bf16 bf16x8 __attribute__((ext_vector_type(8)));
typedef float  f32x4  __attribute__((ext_vector_type(4)));
typedef unsigned short u16;
typedef unsigned int   u32;
typedef unsigned long long u64;

__device__ __forceinline__ float bf2f(u16 u) {
  union { unsigned int i; float f; } v; v.i = ((unsigned int)u) << 16; return v.f;
}
__device__ __forceinline__ u16 f2bf(float f) {
  union { float f; unsigned int i; } v; v.f = f;
  unsigned int u = v.i;
  return (u16)((u + 0x7fffu + ((u >> 16) & 1u)) >> 16);  // RNE
}
__device__ __forceinline__ bf16x8 ld_bf8(const u16* p) {
  uint4 v = *(const uint4*)p;
  return __builtin_bit_cast(bf16x8, v);
}
__device__ __forceinline__ u64 ldq_coh(const u32* p) {
  return __hip_atomic_load((const u64*)p, __ATOMIC_RELAXED, __HIP_MEMORY_SCOPE_AGENT);
}
__device__ __forceinline__ float sigm(float x) { return 1.f / (1.f + __expf(-x)); }
__device__ __forceinline__ float tanhfast(float x) {
  // 1 - 2/(e^{2x}+1): exact limits at +-inf, ~1e-7 rel error, all v_exp_f32.
  return 1.f - 2.f / (__expf(2.f * x) + 1.f);
}

// load 8 weights as bf16x8 from either f32 or bf16 source (flat element offset)
__device__ __forceinline__ bf16x8 ldw8(const void* W, size_t off, bool f32in) {
  if (f32in) {
    const float* p = (const float*)W + off;
    float4 a = *(const float4*)p;
    float4 b = *(const float4*)(p + 4);
    union { u16 s[8]; bf16x8 v; } r;
    r.s[0]=f2bf(a.x); r.s[1]=f2bf(a.y); r.s[2]=f2bf(a.z); r.s[3]=f2bf(a.w);
    r.s[4]=f2bf(b.x); r.s[5]=f2bf(b.y); r.s[6]=f2bf(b.z); r.s[7]=f2bf(b.w);
    return r.v;
  }
  return ld_bf8((const u16*)W + off);
}
__device__ __forceinline__ float ldb1(const void* p, int i, bool f32in) {
  return f32in ? ((const float*)p)[i] : bf2f(((const u16*)p)[i]);
}

// Poll NF fragments (8 tagged u32 words each, stride 32 words between frags)
// until every word carries `tag` in its hi16, then unpack lo16s into bf16x8.
// Tag IS the readiness flag: no producer drain, no separate flag, no barrier.
// obase must include the per-lane ksub quad offset (bug fixed from R2).
template<int NF>
__device__ __forceinline__ void poll_frags(const u32* row, int obase, u32 tag,
                                           bf16x8* out) {
  u64 q[NF * 4];
  for (;;) {
    #pragma unroll
    for (int it = 0; it < NF; ++it) {
      const u32* p = row + obase + it * 32;
      q[it*4+0] = ldq_coh(p + 0); q[it*4+1] = ldq_coh(p + 2);
      q[it*4+2] = ldq_coh(p + 4); q[it*4+3] = ldq_coh(p + 6);
    }
    u64 bad = 0;
    #pragma unroll
    for (int i = 0; i < NF * 4; ++i)
      bad |= (((q[i] >> 16) & 0xffffu) ^ (u64)tag) | ((q[i] >> 48) ^ (u64)tag);
    if (!bad) break;
    __builtin_amdgcn_s_sleep(1);
  }
  #pragma unroll
  for (int it = 0; it < NF; ++it) {
    union { u32 w[4]; bf16x8 v; } r;
    #pragma unroll
    for (int j = 0; j < 4; ++j) {
      const u64 qq = q[it*4+j];
      r.w[j] = ((u32)qq & 0xffffu) | (((u32)(qq >> 32)) << 16);
    }
    out[it] = r.v;
  }
}

// ---- dtype probe: enc_bih0 uniform(-1/32,1/32): bf16 => exponent<=122 always.
__global__ void probe_k(const u16* __restrict__ s, int* __restrict__ flag) {
  if (threadIdx.x == 0) {
    int cnt = 0;
    for (int i = 0; i < 256; ++i) {
      int e = (s[i] >> 7) & 0xFF;
      if (e >= 124) ++cnt;
    }
    flag[0] = (cnt >= 16) ? 1 : 0;
  }
}

__global__ void cvt_k(const void* __restrict__ src, u16* __restrict__ dst, int n,
                      const int* __restrict__ flagp) {
  int i = blockIdx.x * blockDim.x + threadIdx.x;
  if (i >= n) return;
  if (*flagp) dst[i] = f2bf(((const float*)src)[i]);
  else        dst[i] = ((const u16*)src)[i];
}

// ---------------- persistent seq2seq kernel ----------------
// Tag scheme (global dstep g; enc g=0..1023, dec g=1024..2047): stored word =
// ((g+1)<<16)|bf16; expected tag derived per reader below. Rings: 4 slots,
// slot = local_dstep & 3. Initial h/c zeros: zslot (tag 0, memset).
struct PersistArgs {
  const int* tok;
  const u16 *eemb, *demb;                 // normalized bf16 (V,512)
  const void *Wih[4], *Whh[4], *bih[4], *bhh[4];  // idx = phase*2+layer
  const u32 *zslot;                       // (B,H) tagged zeros, tag 0
  u32 *he0, *he1, *hd0, *hd1;             // rings: 4 x (B,H) tagged u32
  u16 *seq;                               // (B,T,H) dec layer1 h (plain bf16)
  u32 *prog;                              // 64 entries, 64 B apart: l1 progress
  const int *dflag;
};

struct PhaseP {
  const void *Wx, *Wh, *bi, *bh;
  const u16* emb;
  const int* tok;
  u32 *r0, *r1;                 // ring bases (this phase)
  const u32 *h0init, *h1init;   // tag gbase slots
  u16* seq;                     // non-null only for dec layer1
  u32 *prog;
  bool f32in, init_c;
  int c0, bid, tid;
  u32 gbase;                    // 0 enc, 1024 dec
};

template<int LAYER>
__device__ void run_phase(const PhaseP& q, f32x4* red4, float* gbuf, float* cbuf,
                          float* bbuf) {
  constexpr int KX = LAYER ? 1024 : 512;
  constexpr int NX = KX / 256;            // frags per wave in x-segment
  constexpr int SLOTN = 16 * 1024;        // u32 per ring slot
  const int tid = q.tid, w = tid >> 6, l = tid & 63;
  const int rr = l & 15, ksub = (l >> 4) * 8;

  // ---- stage weights into registers (held for the whole phase) ----
  bf16x8 BX[4][NX], BH[4][4];
  #pragma unroll
  for (int g = 0; g < 4; ++g) {
    const size_t row = (size_t)(g * 1024 + q.c0 + rr);
    #pragma unroll
    for (int it = 0; it < NX; ++it)
      BX[g][it] = ldw8(q.Wx, row * KX + w * (KX / 8) + it * 32 + ksub, q.f32in);
    #pragma unroll
    for (int it = 0; it < 4; ++it)
      BH[g][it] = ldw8(q.Wh, row * 1024 + w * 128 + it * 32 + ksub, q.f32in);
  }
  if (tid < 64) {
    const int row = (tid >> 4) * 1024 + q.c0 + (tid & 15);
    bbuf[tid] = ldb1(q.bi, row, q.f32in) + ldb1(q.bh, row, q.f32in);
  }
  if (q.init_c && tid < 64) {
    #pragma unroll
    for (int k = 0; k < 4; ++k) cbuf[k * 64 + tid] = 0.f;
  }
  __syncthreads();

  int tok_cur = LAYER ? 0 : q.tok[rr * T_];
  const int s0 = LAYER ? 1 : 0;
  const int s1 = LAYER ? T_ : T_ - 1;

  for (int s = s0; s <= s1; ++s) {
    bf16x8 ax[NX], ah[4];
    if (LAYER == 0) {
      // x from emb: static, cached
      const u16* xrow = q.emb + (size_t)tok_cur * 512;
      #pragma unroll
      for (int it = 0; it < NX; ++it)
        ax[it] = ld_bf8(xrow + w * (KX / 8) + it * 32 + ksub);
      // h = own-layer dstep s-1 (tag gbase+s); s==0 -> tagged zeros (tag gbase)
      const u32* hrow = (s == 0) ? (q.h0init + rr * H_)
                                 : (q.r0 + ((s - 1) & 3) * SLOTN + rr * H_);
      poll_frags<4>(hrow, w * 128 + ksub, q.gbase + (u32)s, ah);
      // overwrite guard: before writing slot s&3 (holds dstep s-4), all 64
      // layer1 blocks must have consumed dstep s-4 (prog >= gbase+s-3).
      if (s >= 4 && tid < 64) {
        const u32 need = q.gbase + (u32)(s - 3);
        while (__hip_atomic_load(&q.prog[tid * 16], __ATOMIC_RELAXED,
                                 __HIP_MEMORY_SCOPE_AGENT) < need)
          __builtin_amdgcn_s_sleep(8);
      }
    } else {
      // x = layer0 dstep s-1 (tag gbase+s)
      const u32* xrow = q.r0 + ((s - 1) & 3) * SLOTN + rr * H_;
      poll_frags<NX>(xrow, w * (KX / 8) + ksub, q.gbase + (u32)s, ax);
      // h = own dstep s-2 (tag gbase+s-1); s==1 -> phase init (tag gbase)
      const u32* hrow = (s == 1) ? (q.h1init + rr * H_)
                                 : (q.r1 + ((s - 2) & 3) * SLOTN + rr * H_);
      poll_frags<4>(hrow, w * 128 + ksub, q.gbase + (u32)(s - 1), ah);
    }
    #pragma unroll
    for (int g = 0; g < 4; ++g) {
      f32x4 acc = {0.f, 0.f, 0.f, 0.f};
      #pragma unroll
      for (int it = 0; it < NX; ++it)
        acc = __builtin_amdgcn_mfma_f32_16x16x32_bf16(ax[it], BX[g][it], acc, 0, 0, 0);
      #pragma unroll
      for (int it = 0; it < 4; ++it)
        acc = __builtin_amdgcn_mfma_f32_16x16x32_bf16(ah[it], BH[g][it], acc, 0, 0, 0);
      red4[(w * 4 + g) * 64 + l] = acc;
    }
    if (LAYER == 0)   // prefetch next step's tokens (pure input)
      tok_cur = q.tok[rr * T_ + ((s + 1 < T_) ? s + 1 : T_ - 1)];
    __syncthreads();
    // publish AFTER barrier: all this block's x loads have completed, so
    // layer0 may overwrite the slot we just consumed.
    if (LAYER == 1 && tid == 0)
      __hip_atomic_store(&q.prog[(q.bid & 63) * 16], q.gbase + (u32)s,
                         __ATOMIC_RELAXED, __HIP_MEMORY_SCOPE_AGENT);
    if (tid < 256) {                     // K-split reduction + bias
      const int g = tid >> 6, ll = tid & 63;
      f32x4 ssum = {0.f, 0.f, 0.f, 0.f};
      #pragma unroll
      for (int w8 = 0; w8 < 8; ++w8) ssum += red4[(w8 * 4 + g) * 64 + ll];
      const int n = ll & 15, mg = (ll >> 4) * 4;
      const float bsum = bbuf[g * 16 + n];
      #pragma unroll
      for (int r = 0; r < 4; ++r) gbuf[(g * 16 + n) * 17 + mg + r] = ssum[r] + bsum;
    }
    __syncthreads();
    if (tid < 64) {                      // LSTM pointwise; 4 cols per thread
      const int m = tid & 15, jg = tid >> 4;
      const u32 stag = LAYER ? (q.gbase + (u32)s) : (q.gbase + (u32)(s + 1));
      u32 wv[4];
      #pragma unroll
      for (int k = 0; k < 4; ++k) {
        const int col = jg * 4 + k;
        const float iv = sigm(gbuf[( 0 + col) * 17 + m]);
        const float fv = sigm(gbuf[(16 + col) * 17 + m]);
        const float gv = tanhfast(gbuf[(32 + col) * 17 + m]);
        const float ov = sigm(gbuf[(48 + col) * 17 + m]);
        const float cn = fv * cbuf[k * 64 + tid] + iv * gv;
        cbuf[k * 64 + tid] = cn;
        wv[k] = (stag << 16) | (u32)f2bf(ov * tanhfast(cn));
      }
      u32* outs = LAYER ? (q.r1 + ((s - 1) & 3) * SLOTN)
                        : (q.r0 + (s & 3) * SLOTN);
      u64* dst = (u64*)(outs + (size_t)m * H_ + q.c0 + jg * 4);
      __hip_atomic_store(dst,     (u64)wv[0] | ((u64)wv[1] << 32),
                         __ATOMIC_RELAXED, __HIP_MEMORY_SCOPE_AGENT);
      __hip_atomic_store(dst + 1, (u64)wv[2] | ((u64)wv[3] << 32),
                         __ATOMIC_RELAXED, __HIP_MEMORY_SCOPE_AGENT);
      if (q.seq) {
        union { u16 s4[4]; u64 q8; } hp;
        #pragma unroll
        for (int k = 0; k < 4; ++k) hp.s4[k] = (u16)(wv[k] & 0xffffu);
        const int t = s - 1;             // only dec layer1 has q.seq
        *(u64*)(q.seq + ((size_t)m * T_ + t) * H_ + q.c0 + jg * 4) = hp.q8;
      }
    }
    // no grid barrier: next iteration's tag polls are the synchronization.
  }
}

__global__ __launch_bounds__(512, 2) void persist_k(PersistArgs P) {
  __shared__ f32x4 red4[32 * 64];   // 32 KB
  __shared__ float gbuf[64 * 17];   // 4.25 KB
  __shared__ float cbuf[4 * 64];    // c-state, carried enc->dec
  __shared__ float bbuf[64];
  const int bid = blockIdx.x, tid = threadIdx.x;
  const int layer = bid >> 6;
  const int c0 = (bid & 63) * 16;
  const bool f32in = (*P.dflag != 0);
  constexpr int SLOTN = 16 * 1024;

  for (int ph = 0; ph < 2; ++ph) {
    PhaseP q;
    const int wi = ph * 2 + layer;
    q.Wx = P.Wih[wi]; q.Wh = P.Whh[wi]; q.bi = P.bih[wi]; q.bh = P.bhh[wi];
    q.emb = ph ? P.demb : P.eemb;
    q.tok = P.tok;
    q.r0 = ph ? P.hd0 : P.he0;
    q.r1 = ph ? P.hd1 : P.he1;
    // enc: tagged zeros (tag 0). dec: enc final h = dstep 1023 -> slot 3, tag 1024.
    q.h0init = ph ? (P.he0 + 3 * SLOTN) : P.zslot;
    q.h1init = ph ? (P.he1 + 3 * SLOTN) : P.zslot;
    q.seq = (ph == 1 && layer == 1) ? P.seq : nullptr;
    q.prog = P.prog;
    q.f32in = f32in; q.init_c = (ph == 0);
    q.c0 = c0; q.bid = bid; q.tid = tid;
    q.gbase = ph ? 1024u : 0u;
    if (layer) run_phase<1>(q, red4, gbuf, cbuf, bbuf);
    else       run_phase<0>(q, red4, gbuf, cbuf, bbuf);
  }
}

// logits[b,c,t] = seq[b,t,:] . outW[c,:] + outb[c]; one wave per 16x16 tile.
__global__ __launch_bounds__(256) void logits_k(const u16* __restrict__ A,
                                                const u16* __restrict__ W,
                                                const u16* __restrict__ bias,
                                                void* __restrict__ out,
                                                const int* __restrict__ dflag) {
  const int wid  = blockIdx.x * 4 + (threadIdx.x >> 6);
  const int mt   = wid >> 4;
  const int nt   = wid & 15;
  const int lane = threadIdx.x & 63;
  const int l15  = lane & 15;
  const int quad = lane >> 4;
  const int ko   = quad * 8;
  const u16* arow = A + (size_t)(mt * 16 + l15) * H_;
  const u16* brow = W + (size_t)(nt * 16 + l15) * H_;
  f32x4 acc = {0.f,0.f,0.f,0.f};
  #pragma unroll 4
  for (int kk = 0; kk < H_; kk += 32) {
    acc = __builtin_amdgcn_mfma_f32_16x16x32_bf16(ld_bf8(arow + kk + ko),
                                                  ld_bf8(brow + kk + ko), acc, 0, 0, 0);
  }
  const int c  = nt * 16 + l15;
  const float bv = bf2f(bias[c]);
  const int f32out = *dflag;
  #pragma unroll
  for (int r = 0; r < 4; ++r) {
    const int m = mt * 16 + quad * 4 + r;
    const int b = m >> 10, t = m & 1023;
    const size_t idx = ((size_t)b * C_ + c) * T_ + t;
    const float v = acc[r] + bv;
    if (f32out) ((float*)out)[idx] = v;
    else        ((u16*)out)[idx]   = f2bf(v);
  }
}

extern "C" void kernel_launch(void* const* d_in, const int* in_sizes, int n_in,
                              void* d_out, int out_size, void* d_ws, size_t ws_size,
                              hipStream_t stream) {
  (void)in_sizes; (void)n_in; (void)out_size; (void)ws_size;

  const int* x = (const int*)d_in[0];

  // ---- workspace layout (~35.7 MiB) ----
  char* ws = (char*)d_ws;
  u32* prog   = (u32*)ws;                       // 16 KiB (64 entries, 64 B apart)
  int* dflag  = (int*)(ws + 16384);             // 256 B
  u32* zslot  = (u32*)(ws + 16640);             // 64 KiB tagged zeros
  u32* rings  = (u32*)(ws + 82176);             // 4 rings x 4 slots x 64 KiB = 1 MiB
  char* base  = ws + 1130752;
  size_t ob = 0;
  u16* p_eemb = (u16*)(base + ob); ob += (size_t)V_ * E_ * 2;
  u16* p_demb = (u16*)(base + ob); ob += (size_t)V_ * E_ * 2;
  u16* p_outW = (u16*)(base + ob); ob += (size_t)C_ * H_ * 2;
  u16* p_outb = (u16*)(base + ob); ob += 512;
  u16* seq    = (u16*)(base + ob); ob += (size_t)B_ * T_ * H_ * 2;
  const size_t RING = 4 * (size_t)16 * 1024;    // u32 per ring

  // zero prog + dflag + zslot + rings (tags reset every launch — stale tags
  // from a previous run must never match)
  hipMemsetAsync(ws, 0, 1130752, stream);

  // dtype probe on enc_bih0 (d_in[5])
  probe_k<<<1, 64, 0, stream>>>((const u16*)d_in[5], dflag);

  // normalize embeddings + output head to bf16
  cvt_k<<<(V_ * E_ + 255) / 256, 256, 0, stream>>>(d_in[1], p_eemb, V_ * E_, dflag);
  cvt_k<<<(V_ * E_ + 255) / 256, 256, 0, stream>>>(d_in[2], p_demb, V_ * E_, dflag);
  cvt_k<<<(C_ * H_ + 255) / 256, 256, 0, stream>>>(d_in[19], p_outW, C_ * H_, dflag);
  cvt_k<<<1, 256, 0, stream>>>(d_in[20], p_outb, C_, dflag);

  PersistArgs P;
  P.tok = x; P.eemb = p_eemb; P.demb = p_demb;
  for (int l = 0; l < 4; ++l) {   // input order: enc0, enc1, dec0, dec1
    P.Wih[l] = d_in[3 + 4 * l + 0];
    P.Whh[l] = d_in[3 + 4 * l + 1];
    P.bih[l] = d_in[3 + 4 * l + 2];
    P.bhh[l] = d_in[3 + 4 * l + 3];
  }
  P.zslot = zslot;
  P.he0 = rings + 0 * RING;
  P.he1 = rings + 1 * RING;
  P.hd0 = rings + 2 * RING;
  P.hd1 = rings + 3 * RING;
  P.seq = seq; P.prog = prog; P.dflag = dflag;

  persist_k<<<128, 512, 0, stream>>>(P);

  logits_k<<<4096, 256, 0, stream>>>(seq, p_outW, p_outb, d_out, dflag);
}

// Round 5
// 16988.712 us; speedup vs baseline: 1.6228x; 1.6228x over previous
//
#include <hip/hip_runtime.h>
#include <stdint.h>

#define B_  16
#define T_  1024
#define H_  1024
#define E_  512
#define V_  256
#define C_  256

typedef __bf16 bf16x8 __attribute__((ext_vector_type(8)));
typedef float  f32x4  __attribute__((ext_vector_type(4)));
typedef unsigned int u32x4 __attribute__((ext_vector_type(4)));
typedef unsigned short u16;
typedef unsigned int   u32;
typedef unsigned long long u64;

__device__ __forceinline__ float bf2f(u16 u) {
  union { unsigned int i; float f; } v; v.i = ((unsigned int)u) << 16; return v.f;
}
__device__ __forceinline__ u16 f2bf(float f) {
  union { float f; unsigned int i; } v; v.f = f;
  unsigned int u = v.i;
  return (u16)((u + 0x7fffu + ((u >> 16) & 1u)) >> 16);  // RNE
}
__device__ __forceinline__ bf16x8 ld_bf8(const u16* p) {
  uint4 v = *(const uint4*)p;
  return __builtin_bit_cast(bf16x8, v);
}
__device__ __forceinline__ float sigm(float x) { return 1.f / (1.f + __expf(-x)); }
__device__ __forceinline__ float tanhfast(float x) {
  // 1 - 2/(e^{2x}+1): exact limits at +-inf, ~1e-7 rel error, all v_exp_f32.
  return 1.f - 2.f / (__expf(2.f * x) + 1.f);
}

// Agent-coherent 16B load: the sc1 policy LLVM uses for agent-scope atomic
// loads, but issued as wide dwordx4 ops that pipeline (8B atomic loads were
// the R1/R3 serialized critical path). ext_vector type -> direct VGPR quad.
#define LOADQ(d, p) \
  asm volatile("global_load_dwordx4 %0, %1, off sc1" : "=&v"(d) : "v"(p) : "memory")
// One wait for the whole volley; sched_barrier stops the compiler hoisting
// the (register-only) tag checks above the waitcnt (rule #18).
#define WAITV() do { asm volatile("s_waitcnt vmcnt(0)" ::: "memory"); \
  __builtin_amdgcn_sched_barrier(0); } while (0)

__device__ __forceinline__ u32 tagchk(u32x4 v, u32 tag) {
  return ((v[0] >> 16) ^ tag) | ((v[1] >> 16) ^ tag) |
         ((v[2] >> 16) ^ tag) | ((v[3] >> 16) ^ tag);
}
__device__ __forceinline__ bf16x8 packbf(u32x4 a, u32x4 b) {
  union { u32 w[4]; bf16x8 v; } r;
  r.w[0] = (a[0] & 0xffffu) | (a[1] << 16);
  r.w[1] = (a[2] & 0xffffu) | (a[3] << 16);
  r.w[2] = (b[0] & 0xffffu) | (b[1] << 16);
  r.w[3] = (b[2] & 0xffffu) | (b[3] << 16);
  return r.v;
}

// Poll 4 fragments (8 tagged u32 each, stride 32 words) until every word's
// hi16 == tag. One parallel volley of 8 dwordx4 + a single vmcnt wait per
// retry attempt.
__device__ __forceinline__ void poll4(const u32* p, u32 tag, bf16x8* out) {
  u32x4 a0,b0,a1,b1,a2,b2,a3,b3;
  for (;;) {
    LOADQ(a0,p);      LOADQ(b0,p+4);
    LOADQ(a1,p+32);   LOADQ(b1,p+36);
    LOADQ(a2,p+64);   LOADQ(b2,p+68);
    LOADQ(a3,p+96);   LOADQ(b3,p+100);
    WAITV();
    const u32 bad = tagchk(a0,tag)|tagchk(b0,tag)|tagchk(a1,tag)|tagchk(b1,tag)
                  | tagchk(a2,tag)|tagchk(b2,tag)|tagchk(a3,tag)|tagchk(b3,tag);
    if (!bad) break;
    __builtin_amdgcn_s_sleep(1);
  }
  out[0]=packbf(a0,b0); out[1]=packbf(a1,b1);
  out[2]=packbf(a2,b2); out[3]=packbf(a3,b3);
}

// Joint poll of x (4 frags) and h (4 frags) -- one 16-load volley per retry,
// so l1's detect chain is one RTT instead of two sequential polls.
__device__ __forceinline__ void poll8(const u32* xp, u32 xtag,
                                      const u32* hp, u32 htag,
                                      bf16x8* ax, bf16x8* ah) {
  u32x4 xa0,xb0,xa1,xb1,xa2,xb2,xa3,xb3;
  u32x4 ha0,hb0,ha1,hb1,ha2,hb2,ha3,hb3;
  for (;;) {
    LOADQ(xa0,xp);      LOADQ(xb0,xp+4);
    LOADQ(xa1,xp+32);   LOADQ(xb1,xp+36);
    LOADQ(xa2,xp+64);   LOADQ(xb2,xp+68);
    LOADQ(xa3,xp+96);   LOADQ(xb3,xp+100);
    LOADQ(ha0,hp);      LOADQ(hb0,hp+4);
    LOADQ(ha1,hp+32);   LOADQ(hb1,hp+36);
    LOADQ(ha2,hp+64);   LOADQ(hb2,hp+68);
    LOADQ(ha3,hp+96);   LOADQ(hb3,hp+100);
    WAITV();
    const u32 bad =
        tagchk(xa0,xtag)|tagchk(xb0,xtag)|tagchk(xa1,xtag)|tagchk(xb1,xtag)
      | tagchk(xa2,xtag)|tagchk(xb2,xtag)|tagchk(xa3,xtag)|tagchk(xb3,xtag)
      | tagchk(ha0,htag)|tagchk(hb0,htag)|tagchk(ha1,htag)|tagchk(hb1,htag)
      | tagchk(ha2,htag)|tagchk(hb2,htag)|tagchk(ha3,htag)|tagchk(hb3,htag);
    if (!bad) break;
    __builtin_amdgcn_s_sleep(1);
  }
  ax[0]=packbf(xa0,xb0); ax[1]=packbf(xa1,xb1);
  ax[2]=packbf(xa2,xb2); ax[3]=packbf(xa3,xb3);
  ah[0]=packbf(ha0,hb0); ah[1]=packbf(ha1,hb1);
  ah[2]=packbf(ha2,hb2); ah[3]=packbf(ha3,hb3);
}

// load 8 weights as bf16x8 from either f32 or bf16 source (flat element offset)
__device__ __forceinline__ bf16x8 ldw8(const void* W, size_t off, bool f32in) {
  if (f32in) {
    const float* p = (const float*)W + off;
    float4 a = *(const float4*)p;
    float4 b = *(const float4*)(p + 4);
    union { u16 s[8]; bf16x8 v; } r;
    r.s[0]=f2bf(a.x); r.s[1]=f2bf(a.y); r.s[2]=f2bf(a.z); r.s[3]=f2bf(a.w);
    r.s[4]=f2bf(b.x); r.s[5]=f2bf(b.y); r.s[6]=f2bf(b.z); r.s[7]=f2bf(b.w);
    return r.v;
  }
  return ld_bf8((const u16*)W + off);
}
__device__ __forceinline__ float ldb1(const void* p, int i, bool f32in) {
  return f32in ? ((const float*)p)[i] : bf2f(((const u16*)p)[i]);
}

// ---- dtype probe: enc_bih0 uniform(-1/32,1/32): bf16 => exponent<=122 always.
__global__ void probe_k(const u16* __restrict__ s, int* __restrict__ flag) {
  if (threadIdx.x == 0) {
    int cnt = 0;
    for (int i = 0; i < 256; ++i) {
      int e = (s[i] >> 7) & 0xFF;
      if (e >= 124) ++cnt;
    }
    flag[0] = (cnt >= 16) ? 1 : 0;
  }
}

__global__ void cvt_k(const void* __restrict__ src, u16* __restrict__ dst, int n,
                      const int* __restrict__ flagp) {
  int i = blockIdx.x * blockDim.x + threadIdx.x;
  if (i >= n) return;
  if (*flagp) dst[i] = f2bf(((const float*)src)[i]);
  else        dst[i] = ((const u16*)src)[i];
}

// ---------------- persistent seq2seq kernel ----------------
// Tag scheme (global dstep g; enc g=0..1023, dec g=1024..2047): stored word =
// (tag<<16)|bf16. Rings: 4 slots, slot = local_dstep & 3. Initial h zeros:
// zslot (tag 0, memset).
struct PersistArgs {
  const int* tok;
  const u16 *eemb, *demb;                 // normalized bf16 (V,512)
  const void *Wih[4], *Whh[4], *bih[4], *bhh[4];  // idx = phase*2+layer
  const u32 *zslot;                       // (B,H) tagged zeros, tag 0
  u32 *he0, *he1, *hd0, *hd1;             // rings: 4 x (B,H) tagged u32
  u16 *seq;                               // (B,T,H) dec layer1 h (plain bf16)
  u32 *prog;                              // 64 entries, 64 B apart: l1 progress
  const int *dflag;
};

struct PhaseP {
  const void *Wx, *Wh, *bi, *bh;
  const u16* emb;
  const int* tok;
  u32 *r0, *r1;                 // ring bases (this phase)
  const u32 *h0init, *h1init;   // tag gbase slots
  u16* seq;                     // non-null only for dec layer1
  u32 *prog;
  bool f32in, init_c;
  int c0, bid, tid;
  u32 gbase;                    // 0 enc, 1024 dec
};

template<int LAYER>
__device__ void run_phase(const PhaseP& q, f32x4* red4, float* gbuf, float* cbuf,
                          float* bbuf) {
  constexpr int KX = LAYER ? 1024 : 512;
  constexpr int NX = KX / 256;            // frags per wave in x-segment
  constexpr int SLOTN = 16 * 1024;        // u32 per ring slot
  const int tid = q.tid, w = tid >> 6, l = tid & 63;
  const int rr = l & 15, ksub = (l >> 4) * 8;

  // ---- stage weights into registers (held for the whole phase) ----
  bf16x8 BX[4][NX], BH[4][4];
  #pragma unroll
  for (int g = 0; g < 4; ++g) {
    const size_t row = (size_t)(g * 1024 + q.c0 + rr);
    #pragma unroll
    for (int it = 0; it < NX; ++it)
      BX[g][it] = ldw8(q.Wx, row * KX + w * (KX / 8) + it * 32 + ksub, q.f32in);
    #pragma unroll
    for (int it = 0; it < 4; ++it)
      BH[g][it] = ldw8(q.Wh, row * 1024 + w * 128 + it * 32 + ksub, q.f32in);
  }
  if (tid < 64) {
    const int row = (tid >> 4) * 1024 + q.c0 + (tid & 15);
    bbuf[tid] = ldb1(q.bi, row, q.f32in) + ldb1(q.bh, row, q.f32in);
  }
  if (q.init_c && tid < 64) {
    #pragma unroll
    for (int k = 0; k < 4; ++k) cbuf[k * 64 + tid] = 0.f;
  }
  __syncthreads();

  int tok_cur = LAYER ? 0 : q.tok[rr * T_];
  const int s0 = LAYER ? 1 : 0;
  const int s1 = LAYER ? T_ : T_ - 1;

  for (int s = s0; s <= s1; ++s) {
    bf16x8 ax[NX], ah[4];
    if (LAYER == 0) {
      // x from emb: static, cached
      const u16* xrow = q.emb + (size_t)tok_cur * 512;
      #pragma unroll
      for (int it = 0; it < NX; ++it)
        ax[it] = ld_bf8(xrow + w * (KX / 8) + it * 32 + ksub);
      // h = own-layer dstep s-1 (tag gbase+s); s==0 -> tagged zeros (tag gbase)
      const u32* hrow = (s == 0) ? (q.h0init + rr * H_)
                                 : (q.r0 + ((s - 1) & 3) * SLOTN + rr * H_);
      poll4(hrow + w * 128 + ksub, q.gbase + (u32)s, ah);
    } else {
      // x = layer0 dstep s-1 (tag gbase+s); h = own dstep s-2 (tag gbase+s-1)
      const u32* xrow = q.r0 + ((s - 1) & 3) * SLOTN + rr * H_;
      const u32* hrow = (s == 1) ? (q.h1init + rr * H_)
                                 : (q.r1 + ((s - 2) & 3) * SLOTN + rr * H_);
      poll8(xrow + w * 128 + ksub, q.gbase + (u32)s,
            hrow + w * 128 + ksub, q.gbase + (u32)(s - 1), ax, ah);
    }
    #pragma unroll
    for (int g = 0; g < 4; ++g) {
      f32x4 acc = {0.f, 0.f, 0.f, 0.f};
      #pragma unroll
      for (int it = 0; it < NX; ++it)
        acc = __builtin_amdgcn_mfma_f32_16x16x32_bf16(ax[it], BX[g][it], acc, 0, 0, 0);
      #pragma unroll
      for (int it = 0; it < 4; ++it)
        acc = __builtin_amdgcn_mfma_f32_16x16x32_bf16(ah[it], BH[g][it], acc, 0, 0, 0);
      red4[(w * 4 + g) * 64 + l] = acc;
    }
    if (LAYER == 0)   // prefetch next step's tokens (pure input)
      tok_cur = q.tok[rr * T_ + ((s + 1 < T_) ? s + 1 : T_ - 1)];
    __syncthreads();
    // publish AFTER barrier: all waves' x loads completed, so layer0 may
    // overwrite the slot this block just consumed.
    if (LAYER == 1 && tid == 0)
      __hip_atomic_store(&q.prog[(q.bid & 63) * 16], q.gbase + (u32)s,
                         __ATOMIC_RELAXED, __HIP_MEMORY_SCOPE_AGENT);
    if (tid < 256) {                     // K-split reduction + bias
      const int g = tid >> 6, ll = tid & 63;
      f32x4 ssum = {0.f, 0.f, 0.f, 0.f};
      #pragma unroll
      for (int w8 = 0; w8 < 8; ++w8) ssum += red4[(w8 * 4 + g) * 64 + ll];
      const int n = ll & 15, mg = (ll >> 4) * 4;
      const float bsum = bbuf[g * 16 + n];
      #pragma unroll
      for (int r = 0; r < 4; ++r) gbuf[(g * 16 + n) * 17 + mg + r] = ssum[r] + bsum;
    }
    __syncthreads();
    if (tid < 64) {                      // LSTM pointwise; 4 cols per thread
      const int m = tid & 15, jg = tid >> 4;
      const u32 stag = LAYER ? (q.gbase + (u32)s) : (q.gbase + (u32)(s + 1));
      u32 wv[4];
      #pragma unroll
      for (int k = 0; k < 4; ++k) {
        const int col = jg * 4 + k;
        const float iv = sigm(gbuf[( 0 + col) * 17 + m]);
        const float fv = sigm(gbuf[(16 + col) * 17 + m]);
        const float gv = tanhfast(gbuf[(32 + col) * 17 + m]);
        const float ov = sigm(gbuf[(48 + col) * 17 + m]);
        const float cn = fv * cbuf[k * 64 + tid] + iv * gv;
        cbuf[k * 64 + tid] = cn;
        wv[k] = (stag << 16) | (u32)f2bf(ov * tanhfast(cn));
      }
      // overwrite guard (l0 only, off the MFMA path): before writing slot s&3
      // (holds dstep s-4), all 64 layer1 blocks must have consumed it.
      if (LAYER == 0 && s >= 4) {
        const u32 need = q.gbase + (u32)(s - 3);
        while (__hip_atomic_load(&q.prog[tid * 16], __ATOMIC_RELAXED,
                                 __HIP_MEMORY_SCOPE_AGENT) < need)
          __builtin_amdgcn_s_sleep(2);
      }
      u32* outs = LAYER ? (q.r1 + ((s - 1) & 3) * SLOTN)
                        : (q.r0 + (s & 3) * SLOTN);
      u64* dst = (u64*)(outs + (size_t)m * H_ + q.c0 + jg * 4);
      __hip_atomic_store(dst,     (u64)wv[0] | ((u64)wv[1] << 32),
                         __ATOMIC_RELAXED, __HIP_MEMORY_SCOPE_AGENT);
      __hip_atomic_store(dst + 1, (u64)wv[2] | ((u64)wv[3] << 32),
                         __ATOMIC_RELAXED, __HIP_MEMORY_SCOPE_AGENT);
      if (q.seq) {
        union { u16 s4[4]; u64 q8; } hp;
        #pragma unroll
        for (int k = 0; k < 4; ++k) hp.s4[k] = (u16)(wv[k] & 0xffffu);
        const int t = s - 1;             // only dec layer1 has q.seq
        *(u64*)(q.seq + ((size_t)m * T_ + t) * H_ + q.c0 + jg * 4) = hp.q8;
      }
    }
    // no grid barrier: next iteration's tag polls are the synchronization.
  }
}

__global__ __launch_bounds__(512, 2) void persist_k(PersistArgs P) {
  __shared__ f32x4 red4[32 * 64];   // 32 KB
  __shared__ float gbuf[64 * 17];   // 4.25 KB
  __shared__ float cbuf[4 * 64];    // c-state, carried enc->dec
  __shared__ float bbuf[64];
  const int bid = blockIdx.x, tid = threadIdx.x;
  const int layer = bid >> 6;
  const int c0 = (bid & 63) * 16;
  const bool f32in = (*P.dflag != 0);
  constexpr int SLOTN = 16 * 1024;

  for (int ph = 0; ph < 2; ++ph) {
    PhaseP q;
    const int wi = ph * 2 + layer;
    q.Wx = P.Wih[wi]; q.Wh = P.Whh[wi]; q.bi = P.bih[wi]; q.bh = P.bhh[wi];
    q.emb = ph ? P.demb : P.eemb;
    q.tok = P.tok;
    q.r0 = ph ? P.hd0 : P.he0;
    q.r1 = ph ? P.hd1 : P.he1;
    // enc: tagged zeros (tag 0). dec: enc final states (tag 1024): l0 stored
    // s=1023 -> slot 3; l1 stored s=1024 -> slot 3.
    q.h0init = ph ? (P.he0 + 3 * SLOTN) : P.zslot;
    q.h1init = ph ? (P.he1 + 3 * SLOTN) : P.zslot;
    q.seq = (ph == 1 && layer == 1) ? P.seq : nullptr;
    q.prog = P.prog;
    q.f32in = f32in; q.init_c = (ph == 0);
    q.c0 = c0; q.bid = bid; q.tid = tid;
    q.gbase = ph ? 1024u : 0u;
    if (layer) run_phase<1>(q, red4, gbuf, cbuf, bbuf);
    else       run_phase<0>(q, red4, gbuf, cbuf, bbuf);
  }
}

// logits[b,c,t] = seq[b,t,:] . outW[c,:] + outb[c]; one wave per 16x16 tile.
__global__ __launch_bounds__(256) void logits_k(const u16* __restrict__ A,
                                                const u16* __restrict__ W,
                                                const u16* __restrict__ bias,
                                                void* __restrict__ out,
                                                const int* __restrict__ dflag) {
  const int wid  = blockIdx.x * 4 + (threadIdx.x >> 6);
  const int mt   = wid >> 4;
  const int nt   = wid & 15;
  const int lane = threadIdx.x & 63;
  const int l15  = lane & 15;
  const int quad = lane >> 4;
  const int ko   = quad * 8;
  const u16* arow = A + (size_t)(mt * 16 + l15) * H_;
  const u16* brow = W + (size_t)(nt * 16 + l15) * H_;
  f32x4 acc = {0.f,0.f,0.f,0.f};
  #pragma unroll 4
  for (int kk = 0; kk < H_; kk += 32) {
    acc = __builtin_amdgcn_mfma_f32_16x16x32_bf16(ld_bf8(arow + kk + ko),
                                                  ld_bf8(brow + kk + ko), acc, 0, 0, 0);
  }
  const int c  = nt * 16 + l15;
  const float bv = bf2f(bias[c]);
  const int f32out = *dflag;
  #pragma unroll
  for (int r = 0; r < 4; ++r) {
    const int m = mt * 16 + quad * 4 + r;
    const int b = m >> 10, t = m & 1023;
    const size_t idx = ((size_t)b * C_ + c) * T_ + t;
    const float v = acc[r] + bv;
    if (f32out) ((float*)out)[idx] = v;
    else        ((u16*)out)[idx]   = f2bf(v);
  }
}

extern "C" void kernel_launch(void* const* d_in, const int* in_sizes, int n_in,
                              void* d_out, int out_size, void* d_ws, size_t ws_size,
                              hipStream_t stream) {
  (void)in_sizes; (void)n_in; (void)out_size; (void)ws_size;

  const int* x = (const int*)d_in[0];

  // ---- workspace layout (~35.7 MiB) ----
  char* ws = (char*)d_ws;
  u32* prog   = (u32*)ws;                       // 16 KiB (64 entries, 64 B apart)
  int* dflag  = (int*)(ws + 16384);             // 256 B
  u32* zslot  = (u32*)(ws + 16640);             // 64 KiB tagged zeros
  u32* rings  = (u32*)(ws + 82176);             // 4 rings x 4 slots x 64 KiB = 1 MiB
  char* base  = ws + 1130752;
  size_t ob = 0;
  u16* p_eemb = (u16*)(base + ob); ob += (size_t)V_ * E_ * 2;
  u16* p_demb = (u16*)(base + ob); ob += (size_t)V_ * E_ * 2;
  u16* p_outW = (u16*)(base + ob); ob += (size_t)C_ * H_ * 2;
  u16* p_outb = (u16*)(base + ob); ob += 512;
  u16* seq    = (u16*)(base + ob); ob += (size_t)B_ * T_ * H_ * 2;
  const size_t RING = 4 * (size_t)16 * 1024;    // u32 per ring

  // zero prog + dflag + zslot + rings (tags reset every launch — stale tags
  // from a previous run must never match)
  hipMemsetAsync(ws, 0, 1130752, stream);

  // dtype probe on enc_bih0 (d_in[5])
  probe_k<<<1, 64, 0, stream>>>((const u16*)d_in[5], dflag);

  // normalize embeddings + output head to bf16
  cvt_k<<<(V_ * E_ + 255) / 256, 256, 0, stream>>>(d_in[1], p_eemb, V_ * E_, dflag);
  cvt_k<<<(V_ * E_ + 255) / 256, 256, 0, stream>>>(d_in[2], p_demb, V_ * E_, dflag);
  cvt_k<<<(C_ * H_ + 255) / 256, 256, 0, stream>>>(d_in[19], p_outW, C_ * H_, dflag);
  cvt_k<<<1, 256, 0, stream>>>(d_in[20], p_outb, C_, dflag);

  PersistArgs P;
  P.tok = x; P.eemb = p_eemb; P.demb = p_demb;
  for (int l = 0; l < 4; ++l) {   // input order: enc0, enc1, dec0, dec1
    P.Wih[l] = d_in[3 + 4 * l + 0];
    P.Whh[l] = d_in[3 + 4 * l + 1];
    P.bih[l] = d_in[3 + 4 * l + 2];
    P.bhh[l] = d_in[3 + 4 * l + 3];
  }
  P.zslot = zslot;
  P.he0 = rings + 0 * RING;
  P.he1 = rings + 1 * RING;
  P.hd0 = rings + 2 * RING;
  P.hd1 = rings + 3 * RING;
  P.seq = seq; P.prog = prog; P.dflag = dflag;

  persist_k<<<128, 512, 0, stream>>>(P);

  logits_k<<<4096, 256, 0, stream>>>(seq, p_outW, p_outb, d_out, dflag);
}

// Round 6
// 14687.460 us; speedup vs baseline: 1.8771x; 1.1567x over previous
//
#include <hip/hip_runtime.h>
#include <stdint.h>

#define B_  16
#define T_  1024
#define H_  1024
#define E_  512
#define V_  256
#define C_  256

typedef __bf16 bf16x8 __attribute__((ext_vector_type(8)));
typedef float  f32x4  __attribute__((ext_vector_type(4)));
typedef unsigned int u32x4 __attribute__((ext_vector_type(4)));
typedef unsigned short u16;
typedef unsigned int   u32;
typedef unsigned long long u64;

__device__ __forceinline__ float bf2f(u16 u) {
  union { unsigned int i; float f; } v; v.i = ((unsigned int)u) << 16; return v.f;
}
__device__ __forceinline__ u16 f2bf(float f) {
  union { float f; unsigned int i; } v; v.f = f;
  unsigned int u = v.i;
  return (u16)((u + 0x7fffu + ((u >> 16) & 1u)) >> 16);  // RNE
}
__device__ __forceinline__ bf16x8 ld_bf8(const u16* p) {
  uint4 v = *(const uint4*)p;
  return __builtin_bit_cast(bf16x8, v);
}
__device__ __forceinline__ float sigm(float x) { return 1.f / (1.f + __expf(-x)); }
__device__ __forceinline__ float tanhfast(float x) {
  // 1 - 2/(e^{2x}+1): exact limits at +-inf, ~1e-7 rel error, all v_exp_f32.
  return 1.f - 2.f / (__expf(2.f * x) + 1.f);
}

// Agent-coherent loads: sc1 policy (what LLVM emits for agent-scope atomics),
// issued as wide ops that pipeline. One waitcnt per volley; sched_barrier
// keeps the tag checks after the wait (rule #18).
#define LOADQ(d, p) \
  asm volatile("global_load_dwordx4 %0, %1, off sc1" : "=&v"(d) : "v"(p) : "memory")
#define LOADD(d, p) \
  asm volatile("global_load_dword %0, %1, off sc1" : "=v"(d) : "v"(p) : "memory")
#define WAITV() do { asm volatile("s_waitcnt vmcnt(0)" ::: "memory"); \
  __builtin_amdgcn_sched_barrier(0); } while (0)

__device__ __forceinline__ u32 tagchk(u32x4 v, u32 tag) {
  return ((v[0] >> 16) ^ tag) | ((v[1] >> 16) ^ tag) |
         ((v[2] >> 16) ^ tag) | ((v[3] >> 16) ^ tag);
}
__device__ __forceinline__ bf16x8 packbf(u32x4 a, u32x4 b) {
  union { u32 w[4]; bf16x8 v; } r;
  r.w[0] = (a[0] & 0xffffu) | (a[1] << 16);
  r.w[1] = (a[2] & 0xffffu) | (a[3] << 16);
  r.w[2] = (b[0] & 0xffffu) | (b[1] << 16);
  r.w[3] = (b[2] & 0xffffu) | (b[3] << 16);
  return r.v;
}

// ---- canary detect (wave 0 only): lane p polls ONE tagged data word of
// producer p (slot[p*16] = row 0, col p*16 -- part of p's thread-0 store).
// 256B per retry instead of 64-128KB: kills the R5 poll-traffic storm.
// Data tag-check at fetch time remains the correctness backstop.
__device__ __forceinline__ void canary1(const u32* slot, u32 tag, int lane) {
  const u32* p = slot + lane * 16;
  for (;;) {
    u32 v;
    LOADD(v, p);
    WAITV();
    if (__all((int)((v >> 16) == tag))) return;
    __builtin_amdgcn_s_sleep(4);
  }
}
__device__ __forceinline__ void canary2(const u32* s1, u32 t1,
                                        const u32* s2, u32 t2, int lane) {
  const u32* p1 = s1 + lane * 16;
  const u32* p2 = s2 + lane * 16;
  for (;;) {
    u32 v1, v2;
    LOADD(v1, p1);
    LOADD(v2, p2);
    WAITV();
    if (__all((int)(((v1 >> 16) == t1) & ((v2 >> 16) == t2)))) return;
    __builtin_amdgcn_s_sleep(4);
  }
}

// Fetch 4 fragments (8 tagged u32 each, stride 32 words); volley of 8
// dwordx4 + one wait. After canary detect this nearly always passes on the
// first try; the loop is the visibility-skew backstop.
__device__ __forceinline__ void poll4(const u32* p, u32 tag, bf16x8* out) {
  u32x4 a0,b0,a1,b1,a2,b2,a3,b3;
  for (;;) {
    LOADQ(a0,p);      LOADQ(b0,p+4);
    LOADQ(a1,p+32);   LOADQ(b1,p+36);
    LOADQ(a2,p+64);   LOADQ(b2,p+68);
    LOADQ(a3,p+96);   LOADQ(b3,p+100);
    WAITV();
    const u32 bad = tagchk(a0,tag)|tagchk(b0,tag)|tagchk(a1,tag)|tagchk(b1,tag)
                  | tagchk(a2,tag)|tagchk(b2,tag)|tagchk(a3,tag)|tagchk(b3,tag);
    if (!bad) break;
    __builtin_amdgcn_s_sleep(1);
  }
  out[0]=packbf(a0,b0); out[1]=packbf(a1,b1);
  out[2]=packbf(a2,b2); out[3]=packbf(a3,b3);
}

// Joint fetch of x (4 frags) and h (4 frags) -- one 16-load volley.
__device__ __forceinline__ void poll8(const u32* xp, u32 xtag,
                                      const u32* hp, u32 htag,
                                      bf16x8* ax, bf16x8* ah) {
  u32x4 xa0,xb0,xa1,xb1,xa2,xb2,xa3,xb3;
  u32x4 ha0,hb0,ha1,hb1,ha2,hb2,ha3,hb3;
  for (;;) {
    LOADQ(xa0,xp);      LOADQ(xb0,xp+4);
    LOADQ(xa1,xp+32);   LOADQ(xb1,xp+36);
    LOADQ(xa2,xp+64);   LOADQ(xb2,xp+68);
    LOADQ(xa3,xp+96);   LOADQ(xb3,xp+100);
    LOADQ(ha0,hp);      LOADQ(hb0,hp+4);
    LOADQ(ha1,hp+32);   LOADQ(hb1,hp+36);
    LOADQ(ha2,hp+64);   LOADQ(hb2,hp+68);
    LOADQ(ha3,hp+96);   LOADQ(hb3,hp+100);
    WAITV();
    const u32 bad =
        tagchk(xa0,xtag)|tagchk(xb0,xtag)|tagchk(xa1,xtag)|tagchk(xb1,xtag)
      | tagchk(xa2,xtag)|tagchk(xb2,xtag)|tagchk(xa3,xtag)|tagchk(xb3,xtag)
      | tagchk(ha0,htag)|tagchk(hb0,htag)|tagchk(ha1,htag)|tagchk(hb1,htag)
      | tagchk(ha2,htag)|tagchk(hb2,htag)|tagchk(ha3,htag)|tagchk(hb3,htag);
    if (!bad) break;
    __builtin_amdgcn_s_sleep(1);
  }
  ax[0]=packbf(xa0,xb0); ax[1]=packbf(xa1,xb1);
  ax[2]=packbf(xa2,xb2); ax[3]=packbf(xa3,xb3);
  ah[0]=packbf(ha0,hb0); ah[1]=packbf(ha1,hb1);
  ah[2]=packbf(ha2,hb2); ah[3]=packbf(ha3,hb3);
}

// load 8 weights as bf16x8 from either f32 or bf16 source (flat element offset)
__device__ __forceinline__ bf16x8 ldw8(const void* W, size_t off, bool f32in) {
  if (f32in) {
    const float* p = (const float*)W + off;
    float4 a = *(const float4*)p;
    float4 b = *(const float4*)(p + 4);
    union { u16 s[8]; bf16x8 v; } r;
    r.s[0]=f2bf(a.x); r.s[1]=f2bf(a.y); r.s[2]=f2bf(a.z); r.s[3]=f2bf(a.w);
    r.s[4]=f2bf(b.x); r.s[5]=f2bf(b.y); r.s[6]=f2bf(b.z); r.s[7]=f2bf(b.w);
    return r.v;
  }
  return ld_bf8((const u16*)W + off);
}
__device__ __forceinline__ float ldb1(const void* p, int i, bool f32in) {
  return f32in ? ((const float*)p)[i] : bf2f(((const u16*)p)[i]);
}

// ---- dtype probe: enc_bih0 uniform(-1/32,1/32): bf16 => exponent<=122 always.
__global__ void probe_k(const u16* __restrict__ s, int* __restrict__ flag) {
  if (threadIdx.x == 0) {
    int cnt = 0;
    for (int i = 0; i < 256; ++i) {
      int e = (s[i] >> 7) & 0xFF;
      if (e >= 124) ++cnt;
    }
    flag[0] = (cnt >= 16) ? 1 : 0;
  }
}

__global__ void cvt_k(const void* __restrict__ src, u16* __restrict__ dst, int n,
                      const int* __restrict__ flagp) {
  int i = blockIdx.x * blockDim.x + threadIdx.x;
  if (i >= n) return;
  if (*flagp) dst[i] = f2bf(((const float*)src)[i]);
  else        dst[i] = ((const u16*)src)[i];
}

// ---------------- persistent seq2seq kernel ----------------
// Tag scheme (global dstep g; enc g=0..1023, dec g=1024..2047): stored word =
// (tag<<16)|bf16. Rings: 4 slots, slot = local_dstep & 3. Initial h zeros:
// zslot (tag 0, memset).
struct PersistArgs {
  const int* tok;
  const u16 *eemb, *demb;                 // normalized bf16 (V,512)
  const void *Wih[4], *Whh[4], *bih[4], *bhh[4];  // idx = phase*2+layer
  const u32 *zslot;                       // (B,H) tagged zeros, tag 0
  u32 *he0, *he1, *hd0, *hd1;             // rings: 4 x (B,H) tagged u32
  u16 *seq;                               // (B,T,H) dec layer1 h (plain bf16)
  u32 *prog;                              // 64 entries, 64 B apart: l1 progress
  const int *dflag;
};

struct PhaseP {
  const void *Wx, *Wh, *bi, *bh;
  const u16* emb;
  const int* tok;
  u32 *r0, *r1;                 // ring bases (this phase)
  const u32 *h0init, *h1init;   // tag gbase slots
  u16* seq;                     // non-null only for dec layer1
  u32 *prog;
  bool f32in, init_c;
  int c0, bid, tid;
  u32 gbase;                    // 0 enc, 1024 dec
};

template<int LAYER>
__device__ void run_phase(const PhaseP& q, f32x4* red4, float* gbuf, float* cbuf,
                          float* bbuf) {
  constexpr int KX = LAYER ? 1024 : 512;
  constexpr int NX = KX / 256;            // frags per wave in x-segment
  constexpr int SLOTN = 16 * 1024;        // u32 per ring slot
  const int tid = q.tid, w = tid >> 6, l = tid & 63;
  const int rr = l & 15, ksub = (l >> 4) * 8;

  // ---- stage weights into registers (held for the whole phase) ----
  bf16x8 BX[4][NX], BH[4][4];
  #pragma unroll
  for (int g = 0; g < 4; ++g) {
    const size_t row = (size_t)(g * 1024 + q.c0 + rr);
    #pragma unroll
    for (int it = 0; it < NX; ++it)
      BX[g][it] = ldw8(q.Wx, row * KX + w * (KX / 8) + it * 32 + ksub, q.f32in);
    #pragma unroll
    for (int it = 0; it < 4; ++it)
      BH[g][it] = ldw8(q.Wh, row * 1024 + w * 128 + it * 32 + ksub, q.f32in);
  }
  if (tid < 64) {
    const int row = (tid >> 4) * 1024 + q.c0 + (tid & 15);
    bbuf[tid] = ldb1(q.bi, row, q.f32in) + ldb1(q.bh, row, q.f32in);
  }
  if (q.init_c && tid < 64) {
    #pragma unroll
    for (int k = 0; k < 4; ++k) cbuf[k * 64 + tid] = 0.f;
  }
  __syncthreads();

  int tok_cur = LAYER ? 0 : q.tok[rr * T_];
  const int s0 = LAYER ? 1 : 0;
  const int s1 = LAYER ? T_ : T_ - 1;

  for (int s = s0; s <= s1; ++s) {
    bf16x8 ax[NX], ah[4];
    if (LAYER == 0) {
      // h slot = own-layer dstep s-1 (tag gbase+s); s==0 -> tagged zeros
      const u32* hslot = (s == 0) ? q.h0init : (q.r0 + ((s - 1) & 3) * SLOTN);
      if (w == 0) canary1(hslot, q.gbase + (u32)s, l);
      __syncthreads();                 // wave0 detect releases all waves
      // x from emb: static, cached
      const u16* xrow = q.emb + (size_t)tok_cur * 512;
      #pragma unroll
      for (int it = 0; it < NX; ++it)
        ax[it] = ld_bf8(xrow + w * (KX / 8) + it * 32 + ksub);
      poll4(hslot + rr * H_ + w * 128 + ksub, q.gbase + (u32)s, ah);
    } else {
      // x = layer0 dstep s-1 (tag gbase+s); h = own dstep s-2 (tag gbase+s-1)
      const u32* xslot = q.r0 + ((s - 1) & 3) * SLOTN;
      const u32* hslot = (s == 1) ? q.h1init : (q.r1 + ((s - 2) & 3) * SLOTN);
      if (w == 0) canary2(xslot, q.gbase + (u32)s,
                          hslot, q.gbase + (u32)(s - 1), l);
      __syncthreads();
      poll8(xslot + rr * H_ + w * 128 + ksub, q.gbase + (u32)s,
            hslot + rr * H_ + w * 128 + ksub, q.gbase + (u32)(s - 1), ax, ah);
    }
    #pragma unroll
    for (int g = 0; g < 4; ++g) {
      f32x4 acc = {0.f, 0.f, 0.f, 0.f};
      #pragma unroll
      for (int it = 0; it < NX; ++it)
        acc = __builtin_amdgcn_mfma_f32_16x16x32_bf16(ax[it], BX[g][it], acc, 0, 0, 0);
      #pragma unroll
      for (int it = 0; it < 4; ++it)
        acc = __builtin_amdgcn_mfma_f32_16x16x32_bf16(ah[it], BH[g][it], acc, 0, 0, 0);
      red4[(w * 4 + g) * 64 + l] = acc;
    }
    if (LAYER == 0)   // prefetch next step's tokens (pure input)
      tok_cur = q.tok[rr * T_ + ((s + 1 < T_) ? s + 1 : T_ - 1)];
    __syncthreads();
    // publish AFTER barrier: all waves' x loads completed, so layer0 may
    // overwrite the slot this block just consumed.
    if (LAYER == 1 && tid == 0)
      __hip_atomic_store(&q.prog[(q.bid & 63) * 16], q.gbase + (u32)s,
                         __ATOMIC_RELAXED, __HIP_MEMORY_SCOPE_AGENT);
    if (tid < 256) {                     // K-split reduction + bias
      const int g = tid >> 6, ll = tid & 63;
      f32x4 ssum = {0.f, 0.f, 0.f, 0.f};
      #pragma unroll
      for (int w8 = 0; w8 < 8; ++w8) ssum += red4[(w8 * 4 + g) * 64 + ll];
      const int n = ll & 15, mg = (ll >> 4) * 4;
      const float bsum = bbuf[g * 16 + n];
      #pragma unroll
      for (int r = 0; r < 4; ++r) gbuf[(g * 16 + n) * 17 + mg + r] = ssum[r] + bsum;
    }
    __syncthreads();
    if (tid < 64) {                      // LSTM pointwise; 4 cols per thread
      const int m = tid & 15, jg = tid >> 4;
      const u32 stag = LAYER ? (q.gbase + (u32)s) : (q.gbase + (u32)(s + 1));
      u32 wv[4];
      #pragma unroll
      for (int k = 0; k < 4; ++k) {
        const int col = jg * 4 + k;
        const float iv = sigm(gbuf[( 0 + col) * 17 + m]);
        const float fv = sigm(gbuf[(16 + col) * 17 + m]);
        const float gv = tanhfast(gbuf[(32 + col) * 17 + m]);
        const float ov = sigm(gbuf[(48 + col) * 17 + m]);
        const float cn = fv * cbuf[k * 64 + tid] + iv * gv;
        cbuf[k * 64 + tid] = cn;
        wv[k] = (stag << 16) | (u32)f2bf(ov * tanhfast(cn));
      }
      // overwrite guard (l0 only, off the MFMA path): before writing slot s&3
      // (holds dstep s-4), all 64 layer1 blocks must have consumed it.
      if (LAYER == 0 && s >= 4) {
        const u32 need = q.gbase + (u32)(s - 3);
        while (__hip_atomic_load(&q.prog[tid * 16], __ATOMIC_RELAXED,
                                 __HIP_MEMORY_SCOPE_AGENT) < need)
          __builtin_amdgcn_s_sleep(2);
      }
      u32* outs = LAYER ? (q.r1 + ((s - 1) & 3) * SLOTN)
                        : (q.r0 + (s & 3) * SLOTN);
      u64* dst = (u64*)(outs + (size_t)m * H_ + q.c0 + jg * 4);
      __hip_atomic_store(dst,     (u64)wv[0] | ((u64)wv[1] << 32),
                         __ATOMIC_RELAXED, __HIP_MEMORY_SCOPE_AGENT);
      __hip_atomic_store(dst + 1, (u64)wv[2] | ((u64)wv[3] << 32),
                         __ATOMIC_RELAXED, __HIP_MEMORY_SCOPE_AGENT);
      if (q.seq) {
        union { u16 s4[4]; u64 q8; } hp;
        #pragma unroll
        for (int k = 0; k < 4; ++k) hp.s4[k] = (u16)(wv[k] & 0xffffu);
        const int t = s - 1;             // only dec layer1 has q.seq
        *(u64*)(q.seq + ((size_t)m * T_ + t) * H_ + q.c0 + jg * 4) = hp.q8;
      }
    }
    // no grid barrier: next iteration's canary+tag polls are the sync.
  }
}

__global__ __launch_bounds__(512, 2) void persist_k(PersistArgs P) {
  __shared__ f32x4 red4[32 * 64];   // 32 KB
  __shared__ float gbuf[64 * 17];   // 4.25 KB
  __shared__ float cbuf[4 * 64];    // c-state, carried enc->dec
  __shared__ float bbuf[64];
  const int bid = blockIdx.x, tid = threadIdx.x;
  const int layer = bid >> 6;
  const int c0 = (bid & 63) * 16;
  const bool f32in = (*P.dflag != 0);
  constexpr int SLOTN = 16 * 1024;

  for (int ph = 0; ph < 2; ++ph) {
    PhaseP q;
    const int wi = ph * 2 + layer;
    q.Wx = P.Wih[wi]; q.Wh = P.Whh[wi]; q.bi = P.bih[wi]; q.bh = P.bhh[wi];
    q.emb = ph ? P.demb : P.eemb;
    q.tok = P.tok;
    q.r0 = ph ? P.hd0 : P.he0;
    q.r1 = ph ? P.hd1 : P.he1;
    // enc: tagged zeros (tag 0). dec: enc final states (tag 1024): l0 stored
    // s=1023 -> slot 3; l1 stored s=1024 -> slot 3.
    q.h0init = ph ? (P.he0 + 3 * SLOTN) : P.zslot;
    q.h1init = ph ? (P.he1 + 3 * SLOTN) : P.zslot;
    q.seq = (ph == 1 && layer == 1) ? P.seq : nullptr;
    q.prog = P.prog;
    q.f32in = f32in; q.init_c = (ph == 0);
    q.c0 = c0; q.bid = bid; q.tid = tid;
    q.gbase = ph ? 1024u : 0u;
    if (layer) run_phase<1>(q, red4, gbuf, cbuf, bbuf);
    else       run_phase<0>(q, red4, gbuf, cbuf, bbuf);
  }
}

// logits[b,c,t] = seq[b,t,:] . outW[c,:] + outb[c]; one wave per 16x16 tile.
__global__ __launch_bounds__(256) void logits_k(const u16* __restrict__ A,
                                                const u16* __restrict__ W,
                                                const u16* __restrict__ bias,
                                                void* __restrict__ out,
                                                const int* __restrict__ dflag) {
  const int wid  = blockIdx.x * 4 + (threadIdx.x >> 6);
  const int mt   = wid >> 4;
  const int nt   = wid & 15;
  const int lane = threadIdx.x & 63;
  const int l15  = lane & 15;
  const int quad = lane >> 4;
  const int ko   = quad * 8;
  const u16* arow = A + (size_t)(mt * 16 + l15) * H_;
  const u16* brow = W + (size_t)(nt * 16 + l15) * H_;
  f32x4 acc = {0.f,0.f,0.f,0.f};
  #pragma unroll 4
  for (int kk = 0; kk < H_; kk += 32) {
    acc = __builtin_amdgcn_mfma_f32_16x16x32_bf16(ld_bf8(arow + kk + ko),
                                                  ld_bf8(brow + kk + ko), acc, 0, 0, 0);
  }
  const int c  = nt * 16 + l15;
  const float bv = bf2f(bias[c]);
  const int f32out = *dflag;
  #pragma unroll
  for (int r = 0; r < 4; ++r) {
    const int m = mt * 16 + quad * 4 + r;
    const int b = m >> 10, t = m & 1023;
    const size_t idx = ((size_t)b * C_ + c) * T_ + t;
    const float v = acc[r] + bv;
    if (f32out) ((float*)out)[idx] = v;
    else        ((u16*)out)[idx]   = f2bf(v);
  }
}

extern "C" void kernel_launch(void* const* d_in, const int* in_sizes, int n_in,
                              void* d_out, int out_size, void* d_ws, size_t ws_size,
                              hipStream_t stream) {
  (void)in_sizes; (void)n_in; (void)out_size; (void)ws_size;

  const int* x = (const int*)d_in[0];

  // ---- workspace layout (~35.7 MiB) ----
  char* ws = (char*)d_ws;
  u32* prog   = (u32*)ws;                       // 16 KiB (64 entries, 64 B apart)
  int* dflag  = (int*)(ws + 16384);             // 256 B
  u32* zslot  = (u32*)(ws + 16640);             // 64 KiB tagged zeros
  u32* rings  = (u32*)(ws + 82176);             // 4 rings x 4 slots x 64 KiB = 1 MiB
  char* base  = ws + 1130752;
  size_t ob = 0;
  u16* p_eemb = (u16*)(base + ob); ob += (size_t)V_ * E_ * 2;
  u16* p_demb = (u16*)(base + ob); ob += (size_t)V_ * E_ * 2;
  u16* p_outW = (u16*)(base + ob); ob += (size_t)C_ * H_ * 2;
  u16* p_outb = (u16*)(base + ob); ob += 512;
  u16* seq    = (u16*)(base + ob); ob += (size_t)B_ * T_ * H_ * 2;
  const size_t RING = 4 * (size_t)16 * 1024;    // u32 per ring

  // zero prog + dflag + zslot + rings (tags reset every launch — stale tags
  // from a previous run must never match)
  hipMemsetAsync(ws, 0, 1130752, stream);

  // dtype probe on enc_bih0 (d_in[5])
  probe_k<<<1, 64, 0, stream>>>((const u16*)d_in[5], dflag);

  // normalize embeddings + output head to bf16
  cvt_k<<<(V_ * E_ + 255) / 256, 256, 0, stream>>>(d_in[1], p_eemb, V_ * E_, dflag);
  cvt_k<<<(V_ * E_ + 255) / 256, 256, 0, stream>>>(d_in[2], p_demb, V_ * E_, dflag);
  cvt_k<<<(C_ * H_ + 255) / 256, 256, 0, stream>>>(d_in[19], p_outW, C_ * H_, dflag);
  cvt_k<<<1, 256, 0, stream>>>(d_in[20], p_outb, C_, dflag);

  PersistArgs P;
  P.tok = x; P.eemb = p_eemb; P.demb = p_demb;
  for (int l = 0; l < 4; ++l) {   // input order: enc0, enc1, dec0, dec1
    P.Wih[l] = d_in[3 + 4 * l + 0];
    P.Whh[l] = d_in[3 + 4 * l + 1];
    P.bih[l] = d_in[3 + 4 * l + 2];
    P.bhh[l] = d_in[3 + 4 * l + 3];
  }
  P.zslot = zslot;
  P.he0 = rings + 0 * RING;
  P.he1 = rings + 1 * RING;
  P.hd0 = rings + 2 * RING;
  P.hd1 = rings + 3 * RING;
  P.seq = seq; P.prog = prog; P.dflag = dflag;

  persist_k<<<128, 512, 0, stream>>>(P);

  logits_k<<<4096, 256, 0, stream>>>(seq, p_outW, p_outb, d_out, dflag);
}